// Round 1
// baseline (596.282 us; speedup 1.0000x reference)
//
#include <hip/hip_runtime.h>
#include <hip/hip_bf16.h>
#include <stdint.h>

#define N_TOK 4096
#define C_DIM 1024
#define H_DIM 2048
#define V_DIM 32000
#define NE_MLP 8
#define NE_TOT 10

typedef __attribute__((ext_vector_type(8))) short bf16x8;
typedef __attribute__((ext_vector_type(4))) short bf16x4;
typedef __attribute__((ext_vector_type(4))) float f32x4;

#define BM 128
#define BN 128
// K-step per barrier pair = 64, staged as two BK=32 LDS images (64B rows)
#define HKE 32            // elems per half-K
#define HALF_ELEMS (128 * 32)   // one 128-row x 32-col bf16 image

__device__ __forceinline__ void gload16(const void* g, void* l) {
    __builtin_amdgcn_global_load_lds(
        (const __attribute__((address_space(1))) void*)g,
        (__attribute__((address_space(3))) void*)l,
        16, 0, 0);
}

__device__ __forceinline__ unsigned short bf16bits(float v) {
    __hip_bfloat16 h = __float2bfloat16(v);
    return *reinterpret_cast<unsigned short*>(&h);
}

// ---------------- weights fp32 -> bf16 convert (w_up, w_down) --------------
#define CVT_W (NE_MLP * H_DIM * C_DIM / 4)
__global__ void __launch_bounds__(256) cvt_kernel(
    const float* __restrict__ wu, const float* __restrict__ wd,
    __hip_bfloat16* __restrict__ wub, __hip_bfloat16* __restrict__ wdb)
{
    const int i = blockIdx.x * 256 + threadIdx.x;
    const float* src;
    __hip_bfloat16* dst;
    int j;
    if (i < CVT_W) { src = wu; dst = wub; j = i; }
    else           { src = wd; dst = wdb; j = i - CVT_W; }
    f32x4 v = reinterpret_cast<const f32x4*>(src)[j];
    bf16x4 b;
    b.x = (short)bf16bits(v.x); b.y = (short)bf16bits(v.y);
    b.z = (short)bf16bits(v.z); b.w = (short)bf16bits(v.w);
    reinterpret_cast<bf16x4*>(dst)[j] = b;
}

// ------- router: scores, top-2, expert lists; fused x -> bf16 convert ------
__global__ void __launch_bounds__(256) router_kernel(
    const float* __restrict__ x, const float* __restrict__ rw,
    const float* __restrict__ rb, __hip_bfloat16* __restrict__ xb,
    int* __restrict__ tok_list, float* __restrict__ wlist,
    float* __restrict__ vw, int* __restrict__ cnt)
{
    const int lane = threadIdx.x & 63;
    const int n = blockIdx.x * 4 + (threadIdx.x >> 6);
    const f32x4* xr  = reinterpret_cast<const f32x4*>(x + (size_t)n * C_DIM);
    const f32x4* rw4 = reinterpret_cast<const f32x4*>(rw);
    bf16x4* xbr = reinterpret_cast<bf16x4*>(xb + (size_t)n * C_DIM);

    float acc[NE_TOT];
    #pragma unroll
    for (int e = 0; e < NE_TOT; ++e) acc[e] = 0.f;

    #pragma unroll
    for (int kk = 0; kk < C_DIM / 256; ++kk) {
        f32x4 xv = xr[kk * 64 + lane];
        // fused bf16 conversion of x (row is being read anyway)
        bf16x4 xbv;
        xbv.x = (short)bf16bits(xv.x); xbv.y = (short)bf16bits(xv.y);
        xbv.z = (short)bf16bits(xv.z); xbv.w = (short)bf16bits(xv.w);
        xbr[kk * 64 + lane] = xbv;
        #pragma unroll
        for (int e = 0; e < NE_TOT; ++e) {
            f32x4 wv = rw4[e * (C_DIM / 4) + kk * 64 + lane];
            acc[e] += xv.x * wv.x + xv.y * wv.y + xv.z * wv.z + xv.w * wv.w;
        }
    }
    #pragma unroll
    for (int e = 0; e < NE_TOT; ++e) {
        for (int m = 32; m > 0; m >>= 1) acc[e] += __shfl_xor(acc[e], m, 64);
    }

    if (lane == 0) {
        float s[NE_TOT], sb[NE_TOT];
        #pragma unroll
        for (int e = 0; e < NE_TOT; ++e) {
            s[e]  = 1.f / (1.f + expf(-acc[e]));
            sb[e] = s[e] + rb[e];
        }
        int i0 = 0;
        #pragma unroll
        for (int e = 1; e < NE_TOT; ++e) if (sb[e] > sb[i0]) i0 = e;
        int i1 = (i0 == 0) ? 1 : 0;
        #pragma unroll
        for (int e = 0; e < NE_TOT; ++e)
            if (e != i0 && sb[e] > sb[i1]) i1 = e;

        float w0 = s[i0], w1 = s[i1];
        float inv = 1.f / (w0 + w1);
        w0 *= inv; w1 *= inv;

        float wv0 = 0.f, wv1 = 0.f;
        int   idx[2] = {i0, i1};
        float wt[2]  = {w0, w1};
        #pragma unroll
        for (int k = 0; k < 2; ++k) {
            if (idx[k] < NE_MLP) {
                int p = atomicAdd(&cnt[idx[k]], 1);
                tok_list[idx[k] * N_TOK + p] = n;
                wlist[idx[k] * N_TOK + p] = wt[k];
            } else {
                if (idx[k] == NE_MLP) wv0 = wt[k]; else wv1 = wt[k];
            }
        }
        vw[n * 2 + 0] = wv0;
        vw[n * 2 + 1] = wv1;
    }
}

// ---- ve init: out = ve contribs (runs BEFORE down_kernel's atomics) -------
__global__ void __launch_bounds__(256) ve_kernel(
    const int* __restrict__ token_ids, const float* __restrict__ vt,
    const float* __restrict__ vw, float* __restrict__ out)
{
    const int n = blockIdx.x;
    const int c = threadIdx.x;
    const int t = token_ids[n];
    const float w0 = vw[n * 2 + 0];
    const float w1 = vw[n * 2 + 1];
    f32x4 v = {0.f, 0.f, 0.f, 0.f};
    if (w0 != 0.f)
        v += w0 * reinterpret_cast<const f32x4*>(vt + (size_t)t * C_DIM)[c];
    if (w1 != 0.f)
        v += w1 * reinterpret_cast<const f32x4*>(vt + ((size_t)V_DIM + t) * C_DIM)[c];
    reinterpret_cast<f32x4*>(out + (size_t)n * C_DIM)[c] = v;
}

// ---------------- grouped up-proj: hidden = relu(x @ w_up^T)^2 (bf16 out) ----
__global__ void __launch_bounds__(256) up_kernel(
    const __hip_bfloat16* __restrict__ xb, const __hip_bfloat16* __restrict__ wub,
    const int* __restrict__ tok_list, const int* __restrict__ cnt,
    __hip_bfloat16* __restrict__ hidden)
{
    // bijective XCD swizzle: grid = 16 x 32 x 8 = 4096 blocks, 4096 % 8 == 0
    const int lid = (blockIdx.z * 32 + blockIdx.y) * 16 + blockIdx.x;
    const int s   = (lid & 7) * 512 + (lid >> 3);
    const int bx = s & 15, by = (s >> 4) & 31, bz = s >> 9;

    const int e = bz;
    const int count = cnt[e];
    const int m0 = by * BM;
    if (m0 >= count) return;
    const int n0 = bx * BN;

    __shared__ __hip_bfloat16 lA[2 * HALF_ELEMS];
    __shared__ __hip_bfloat16 lB[2 * HALF_ELEMS];

    const int tid  = threadIdx.x;
    const int lane = tid & 63;
    const int wv   = tid >> 6;
    const int wm = (wv >> 1) * 64;
    const int wn = (wv & 1) * 64;

    const __hip_bfloat16* ga[2];
    const __hip_bfloat16* gb[2];
    __hip_bfloat16* la[2];
    __hip_bfloat16* lb[2];
    const __hip_bfloat16* wB = wub + (size_t)e * H_DIM * C_DIM;
    #pragma unroll
    for (int t = 0; t < 2; ++t) {
        const int srow = (wv + 4 * t) * 16 + (lane >> 2);
        int r = m0 + srow;
        const int tok = tok_list[e * N_TOK + (r < count ? r : count - 1)];
        ga[t] = xb + (size_t)tok * C_DIM + (lane & 3) * 8;
        gb[t] = wB + (size_t)(n0 + srow) * C_DIM + (lane & 3) * 8;
        la[t] = lA + (wv + 4 * t) * 512;
        lb[t] = lB + (wv + 4 * t) * 512;
    }

    f32x4 acc[4][4];
    #pragma unroll
    for (int i = 0; i < 4; ++i)
        #pragma unroll
        for (int j = 0; j < 4; ++j)
            acc[i][j] = (f32x4){0.f, 0.f, 0.f, 0.f};

    const int fm  = lane & 15;
    const int fkb = (lane >> 4) * 8;

    for (int k0 = 0; k0 < C_DIM; k0 += 2 * HKE) {
        __syncthreads();
        #pragma unroll
        for (int h = 0; h < 2; ++h) {
            #pragma unroll
            for (int t = 0; t < 2; ++t) {
                gload16(ga[t] + h * HKE, la[t] + h * HALF_ELEMS);
                gload16(gb[t] + h * HKE, lb[t] + h * HALF_ELEMS);
            }
        }
        #pragma unroll
        for (int t = 0; t < 2; ++t) { ga[t] += 2 * HKE; gb[t] += 2 * HKE; }
        __syncthreads();
        #pragma unroll
        for (int h = 0; h < 2; ++h) {
            bf16x8 af[4], bfr[4];
            #pragma unroll
            for (int i = 0; i < 4; ++i) {
                af[i]  = *reinterpret_cast<const bf16x8*>(lA + h * HALF_ELEMS + (wm + i * 16 + fm) * HKE + fkb);
                bfr[i] = *reinterpret_cast<const bf16x8*>(lB + h * HALF_ELEMS + (wn + i * 16 + fm) * HKE + fkb);
            }
            #pragma unroll
            for (int i = 0; i < 4; ++i)
                #pragma unroll
                for (int j = 0; j < 4; ++j)
                    acc[i][j] = __builtin_amdgcn_mfma_f32_16x16x32_bf16(af[i], bfr[j], acc[i][j], 0, 0, 0);
        }
    }

    const int fr = (lane >> 4) * 4;
    #pragma unroll
    for (int i = 0; i < 4; ++i) {
        #pragma unroll
        for (int r = 0; r < 4; ++r) {
            const int gr = m0 + wm + i * 16 + fr + r;
            const bool ok = gr < count;
            unsigned int pk[4];
            #pragma unroll
            for (int j = 0; j < 4; ++j) {
                float v = acc[i][j][r];
                v = v > 0.f ? v * v : 0.f;
                unsigned short b = bf16bits(v);
                int other = __shfl_xor((int)b, 1, 64);
                pk[j] = (unsigned)b | ((unsigned)other << 16);
            }
            if (ok && !(lane & 1)) {
                __hip_bfloat16* hrow = hidden + (size_t)(e * N_TOK + gr) * H_DIM + n0 + wn + fm;
                #pragma unroll
                for (int j = 0; j < 4; ++j)
                    *reinterpret_cast<unsigned int*>(hrow + j * 16) = pk[j];
            }
        }
    }
}

// ------- grouped down-proj (split-K=2): out += w * (hidden @ w_down^T) -----
__global__ void __launch_bounds__(256) down_kernel(
    const __hip_bfloat16* __restrict__ hidden, const __hip_bfloat16* __restrict__ wdb,
    const int* __restrict__ tok_list, const float* __restrict__ wlist,
    const int* __restrict__ cnt, float* __restrict__ out)
{
    // bijective XCD swizzle: grid = 8 x 32 x 16 = 4096 blocks
    const int lid = (blockIdx.z * 32 + blockIdx.y) * 8 + blockIdx.x;
    const int s   = (lid & 7) * 512 + (lid >> 3);
    const int bx = s & 7, by = (s >> 3) & 31, bz = s >> 8;

    const int e  = bz >> 1;
    const int kh = bz & 1;
    const int count = cnt[e];
    const int m0 = by * BM;
    if (m0 >= count) return;
    const int n0 = bx * BN;
    const int kbase = kh * (H_DIM / 2);

    __shared__ __hip_bfloat16 lA[2 * HALF_ELEMS];
    __shared__ __hip_bfloat16 lB[2 * HALF_ELEMS];

    const int tid  = threadIdx.x;
    const int lane = tid & 63;
    const int wv   = tid >> 6;
    const int wm = (wv >> 1) * 64;
    const int wn = (wv & 1) * 64;

    const __hip_bfloat16* ga[2];
    const __hip_bfloat16* gb[2];
    __hip_bfloat16* la[2];
    __hip_bfloat16* lb[2];
    const __hip_bfloat16* wB = wdb + (size_t)e * C_DIM * H_DIM;
    #pragma unroll
    for (int t = 0; t < 2; ++t) {
        const int srow = (wv + 4 * t) * 16 + (lane >> 2);
        int r = m0 + srow;
        const int arow = e * N_TOK + (r < count ? r : count - 1);
        ga[t] = hidden + (size_t)arow * H_DIM + kbase + (lane & 3) * 8;
        gb[t] = wB + (size_t)(n0 + srow) * H_DIM + kbase + (lane & 3) * 8;
        la[t] = lA + (wv + 4 * t) * 512;
        lb[t] = lB + (wv + 4 * t) * 512;
    }

    f32x4 acc[4][4];
    #pragma unroll
    for (int i = 0; i < 4; ++i)
        #pragma unroll
        for (int j = 0; j < 4; ++j)
            acc[i][j] = (f32x4){0.f, 0.f, 0.f, 0.f};

    const int fm  = lane & 15;
    const int fkb = (lane >> 4) * 8;

    for (int k0 = 0; k0 < H_DIM / 2; k0 += 2 * HKE) {
        __syncthreads();
        #pragma unroll
        for (int h = 0; h < 2; ++h) {
            #pragma unroll
            for (int t = 0; t < 2; ++t) {
                gload16(ga[t] + h * HKE, la[t] + h * HALF_ELEMS);
                gload16(gb[t] + h * HKE, lb[t] + h * HALF_ELEMS);
            }
        }
        #pragma unroll
        for (int t = 0; t < 2; ++t) { ga[t] += 2 * HKE; gb[t] += 2 * HKE; }
        __syncthreads();
        #pragma unroll
        for (int h = 0; h < 2; ++h) {
            bf16x8 af[4], bfr[4];
            #pragma unroll
            for (int i = 0; i < 4; ++i) {
                af[i]  = *reinterpret_cast<const bf16x8*>(lA + h * HALF_ELEMS + (wm + i * 16 + fm) * HKE + fkb);
                bfr[i] = *reinterpret_cast<const bf16x8*>(lB + h * HALF_ELEMS + (wn + i * 16 + fm) * HKE + fkb);
            }
            #pragma unroll
            for (int i = 0; i < 4; ++i)
                #pragma unroll
                for (int j = 0; j < 4; ++j)
                    acc[i][j] = __builtin_amdgcn_mfma_f32_16x16x32_bf16(af[i], bfr[j], acc[i][j], 0, 0, 0);
        }
    }

    // epilogue: weighted atomic scatter straight into out (ve already there)
    const int fr = (lane >> 4) * 4;
    #pragma unroll
    for (int i = 0; i < 4; ++i) {
        #pragma unroll
        for (int r = 0; r < 4; ++r) {
            const int gr = m0 + wm + i * 16 + fr + r;
            if (gr < count) {
                const int   tok = tok_list[e * N_TOK + gr];
                const float w   = wlist[e * N_TOK + gr];
                float* orow = out + (size_t)tok * C_DIM + n0 + wn + fm;
                #pragma unroll
                for (int j = 0; j < 4; ++j)
                    __hip_atomic_fetch_add(orow + j * 16, w * acc[i][j][r],
                                           __ATOMIC_RELAXED, __HIP_MEMORY_SCOPE_AGENT);
            }
        }
    }
}

extern "C" void kernel_launch(void* const* d_in, const int* in_sizes, int n_in,
                              void* d_out, int out_size, void* d_ws, size_t ws_size,
                              hipStream_t stream)
{
    const float* x         = (const float*)d_in[0];
    const int*   token_ids = (const int*)  d_in[1];
    const float* w_up      = (const float*)d_in[2];
    const float* w_down    = (const float*)d_in[3];
    const float* router_w  = (const float*)d_in[4];
    const float* router_b  = (const float*)d_in[5];
    const float* ve_tables = (const float*)d_in[6];
    float* out = (float*)d_out;

    char* ws = (char*)d_ws;
    size_t off = 0;
    __hip_bfloat16* hidden  = (__hip_bfloat16*)(ws + off); off += (size_t)NE_MLP * N_TOK * H_DIM * 2;  // 134 MB
    __hip_bfloat16* xb      = (__hip_bfloat16*)(ws + off); off += (size_t)N_TOK * C_DIM * 2;
    __hip_bfloat16* wub     = (__hip_bfloat16*)(ws + off); off += (size_t)NE_MLP * H_DIM * C_DIM * 2;
    __hip_bfloat16* wdb     = (__hip_bfloat16*)(ws + off); off += (size_t)NE_MLP * C_DIM * H_DIM * 2;
    int*   tok_list = (int*)  (ws + off); off += (size_t)NE_MLP * N_TOK * 4;
    float* wlist    = (float*)(ws + off); off += (size_t)NE_MLP * N_TOK * 4;
    float* vw       = (float*)(ws + off); off += (size_t)N_TOK * 2 * 4;
    int*   cnt      = (int*)  (ws + off); off += 64;

    hipMemsetAsync(cnt, 0, NE_MLP * sizeof(int), stream);

    router_kernel<<<N_TOK / 4, 256, 0, stream>>>(x, router_w, router_b, xb,
                                                 tok_list, wlist, vw, cnt);
    cvt_kernel<<<2 * CVT_W / 256, 256, 0, stream>>>(w_up, w_down, wub, wdb);
    ve_kernel<<<N_TOK, 256, 0, stream>>>(token_ids, ve_tables, vw, out);
    up_kernel<<<dim3(H_DIM / BN, N_TOK / BM, NE_MLP), 256, 0, stream>>>(
        xb, wub, tok_list, cnt, hidden);
    down_kernel<<<dim3(C_DIM / BN, N_TOK / BM, NE_MLP * 2), 256, 0, stream>>>(
        hidden, wdb, tok_list, wlist, cnt, out);
}

// Round 2
// 582.997 us; speedup vs baseline: 1.0228x; 1.0228x over previous
//
#include <hip/hip_runtime.h>
#include <hip/hip_bf16.h>
#include <stdint.h>

#define N_TOK 4096
#define C_DIM 1024
#define H_DIM 2048
#define V_DIM 32000
#define NE_MLP 8
#define NE_TOT 10

typedef __attribute__((ext_vector_type(8))) short bf16x8;
typedef __attribute__((ext_vector_type(4))) short bf16x4;
typedef __attribute__((ext_vector_type(4))) float f32x4;

#define BM 128
#define BN 128
#define BND 64
// K-step per barrier pair = 64, staged as two BK=32 LDS images (64B rows)
#define HKE 32            // elems per half-K
#define HALF_ELEMS (128 * 32)   // one 128-row x 32-col bf16 image
#define HALF_B (64 * 32)        // one 64-row x 32-col bf16 image (down B)

__device__ __forceinline__ void gload16(const void* g, void* l) {
    __builtin_amdgcn_global_load_lds(
        (const __attribute__((address_space(1))) void*)g,
        (__attribute__((address_space(3))) void*)l,
        16, 0, 0);
}

__device__ __forceinline__ unsigned short bf16bits(float v) {
    __hip_bfloat16 h = __float2bfloat16(v);
    return *reinterpret_cast<unsigned short*>(&h);
}

// ---------------- weights fp32 -> bf16 convert (w_up, w_down) --------------
#define CVT_W (NE_MLP * H_DIM * C_DIM / 4)
__global__ void __launch_bounds__(256) cvt_kernel(
    const float* __restrict__ wu, const float* __restrict__ wd,
    __hip_bfloat16* __restrict__ wub, __hip_bfloat16* __restrict__ wdb)
{
    const int i = blockIdx.x * 256 + threadIdx.x;
    const float* src;
    __hip_bfloat16* dst;
    int j;
    if (i < CVT_W) { src = wu; dst = wub; j = i; }
    else           { src = wd; dst = wdb; j = i - CVT_W; }
    f32x4 v = reinterpret_cast<const f32x4*>(src)[j];
    bf16x4 b;
    b.x = (short)bf16bits(v.x); b.y = (short)bf16bits(v.y);
    b.z = (short)bf16bits(v.z); b.w = (short)bf16bits(v.w);
    reinterpret_cast<bf16x4*>(dst)[j] = b;
}

// -- router: scores, top-2, expert lists; fused x->bf16 AND ve-init of out --
__global__ void __launch_bounds__(256) router_kernel(
    const float* __restrict__ x, const float* __restrict__ rw,
    const float* __restrict__ rb, const int* __restrict__ token_ids,
    const float* __restrict__ vt, __hip_bfloat16* __restrict__ xb,
    int* __restrict__ tok_list, float* __restrict__ wlist,
    int* __restrict__ cnt, float* __restrict__ out)
{
    const int lane = threadIdx.x & 63;
    const int n = blockIdx.x * 4 + (threadIdx.x >> 6);
    const f32x4* xr  = reinterpret_cast<const f32x4*>(x + (size_t)n * C_DIM);
    const f32x4* rw4 = reinterpret_cast<const f32x4*>(rw);
    bf16x4* xbr = reinterpret_cast<bf16x4*>(xb + (size_t)n * C_DIM);

    float acc[NE_TOT];
    #pragma unroll
    for (int e = 0; e < NE_TOT; ++e) acc[e] = 0.f;

    #pragma unroll
    for (int kk = 0; kk < C_DIM / 256; ++kk) {
        f32x4 xv = xr[kk * 64 + lane];
        // fused bf16 conversion of x (row is being read anyway)
        bf16x4 xbv;
        xbv.x = (short)bf16bits(xv.x); xbv.y = (short)bf16bits(xv.y);
        xbv.z = (short)bf16bits(xv.z); xbv.w = (short)bf16bits(xv.w);
        xbr[kk * 64 + lane] = xbv;
        #pragma unroll
        for (int e = 0; e < NE_TOT; ++e) {
            f32x4 wv = rw4[e * (C_DIM / 4) + kk * 64 + lane];
            acc[e] += xv.x * wv.x + xv.y * wv.y + xv.z * wv.z + xv.w * wv.w;
        }
    }
    #pragma unroll
    for (int e = 0; e < NE_TOT; ++e) {
        for (int m = 32; m > 0; m >>= 1) acc[e] += __shfl_xor(acc[e], m, 64);
    }

    float wv0 = 0.f, wv1 = 0.f;
    if (lane == 0) {
        float s[NE_TOT], sb[NE_TOT];
        #pragma unroll
        for (int e = 0; e < NE_TOT; ++e) {
            s[e]  = 1.f / (1.f + expf(-acc[e]));
            sb[e] = s[e] + rb[e];
        }
        int i0 = 0;
        #pragma unroll
        for (int e = 1; e < NE_TOT; ++e) if (sb[e] > sb[i0]) i0 = e;
        int i1 = (i0 == 0) ? 1 : 0;
        #pragma unroll
        for (int e = 0; e < NE_TOT; ++e)
            if (e != i0 && sb[e] > sb[i1]) i1 = e;

        float w0 = s[i0], w1 = s[i1];
        float inv = 1.f / (w0 + w1);
        w0 *= inv; w1 *= inv;

        int   idx[2] = {i0, i1};
        float wt[2]  = {w0, w1};
        #pragma unroll
        for (int k = 0; k < 2; ++k) {
            if (idx[k] < NE_MLP) {
                int p = atomicAdd(&cnt[idx[k]], 1);
                tok_list[idx[k] * N_TOK + p] = n;
                wlist[idx[k] * N_TOK + p] = wt[k];
            } else {
                if (idx[k] == NE_MLP) wv0 = wt[k]; else wv1 = wt[k];
            }
        }
    }
    // fused ve-init: out[n] = wv0*vt[0][tok] + wv1*vt[1][tok]  (or zeros)
    wv0 = __shfl(wv0, 0, 64);
    wv1 = __shfl(wv1, 0, 64);
    const int t = token_ids[n];
    const f32x4* v0 = reinterpret_cast<const f32x4*>(vt + (size_t)t * C_DIM);
    const f32x4* v1 = reinterpret_cast<const f32x4*>(vt + ((size_t)V_DIM + t) * C_DIM);
    f32x4* orow = reinterpret_cast<f32x4*>(out + (size_t)n * C_DIM);
    #pragma unroll
    for (int q = 0; q < 4; ++q) {
        const int c = q * 64 + lane;
        f32x4 v = {0.f, 0.f, 0.f, 0.f};
        if (wv0 != 0.f) v += wv0 * v0[c];
        if (wv1 != 0.f) v += wv1 * v1[c];
        orow[c] = v;
    }
}

// ---------------- grouped up-proj: hidden = relu(x @ w_up^T)^2 (bf16 out) ----
__global__ void __launch_bounds__(256) up_kernel(
    const __hip_bfloat16* __restrict__ xb, const __hip_bfloat16* __restrict__ wub,
    const int* __restrict__ tok_list, const int* __restrict__ cnt,
    __hip_bfloat16* __restrict__ hidden)
{
    // bijective XCD swizzle: grid = 16 x 32 x 8 = 4096 blocks, 4096 % 8 == 0
    const int lid = (blockIdx.z * 32 + blockIdx.y) * 16 + blockIdx.x;
    const int s   = (lid & 7) * 512 + (lid >> 3);
    const int bx = s & 15, by = (s >> 4) & 31, bz = s >> 9;

    const int e = bz;
    const int count = cnt[e];
    const int m0 = by * BM;
    if (m0 >= count) return;
    const int n0 = bx * BN;

    __shared__ __hip_bfloat16 lA[2 * HALF_ELEMS];
    __shared__ __hip_bfloat16 lB[2 * HALF_ELEMS];

    const int tid  = threadIdx.x;
    const int lane = tid & 63;
    const int wv   = tid >> 6;
    const int wm = (wv >> 1) * 64;
    const int wn = (wv & 1) * 64;

    const __hip_bfloat16* ga[2];
    const __hip_bfloat16* gb[2];
    __hip_bfloat16* la[2];
    __hip_bfloat16* lb[2];
    const __hip_bfloat16* wB = wub + (size_t)e * H_DIM * C_DIM;
    #pragma unroll
    for (int t = 0; t < 2; ++t) {
        const int srow = (wv + 4 * t) * 16 + (lane >> 2);
        int r = m0 + srow;
        const int tok = tok_list[e * N_TOK + (r < count ? r : count - 1)];
        ga[t] = xb + (size_t)tok * C_DIM + (lane & 3) * 8;
        gb[t] = wB + (size_t)(n0 + srow) * C_DIM + (lane & 3) * 8;
        la[t] = lA + (wv + 4 * t) * 512;
        lb[t] = lB + (wv + 4 * t) * 512;
    }

    f32x4 acc[4][4];
    #pragma unroll
    for (int i = 0; i < 4; ++i)
        #pragma unroll
        for (int j = 0; j < 4; ++j)
            acc[i][j] = (f32x4){0.f, 0.f, 0.f, 0.f};

    const int fm  = lane & 15;
    const int fkb = (lane >> 4) * 8;

    for (int k0 = 0; k0 < C_DIM; k0 += 2 * HKE) {
        __syncthreads();
        #pragma unroll
        for (int h = 0; h < 2; ++h) {
            #pragma unroll
            for (int t = 0; t < 2; ++t) {
                gload16(ga[t] + h * HKE, la[t] + h * HALF_ELEMS);
                gload16(gb[t] + h * HKE, lb[t] + h * HALF_ELEMS);
            }
        }
        #pragma unroll
        for (int t = 0; t < 2; ++t) { ga[t] += 2 * HKE; gb[t] += 2 * HKE; }
        __syncthreads();
        #pragma unroll
        for (int h = 0; h < 2; ++h) {
            bf16x8 af[4], bfr[4];
            #pragma unroll
            for (int i = 0; i < 4; ++i) {
                af[i]  = *reinterpret_cast<const bf16x8*>(lA + h * HALF_ELEMS + (wm + i * 16 + fm) * HKE + fkb);
                bfr[i] = *reinterpret_cast<const bf16x8*>(lB + h * HALF_ELEMS + (wn + i * 16 + fm) * HKE + fkb);
            }
            #pragma unroll
            for (int i = 0; i < 4; ++i)
                #pragma unroll
                for (int j = 0; j < 4; ++j)
                    acc[i][j] = __builtin_amdgcn_mfma_f32_16x16x32_bf16(af[i], bfr[j], acc[i][j], 0, 0, 0);
        }
    }

    const int fr = (lane >> 4) * 4;
    #pragma unroll
    for (int i = 0; i < 4; ++i) {
        #pragma unroll
        for (int r = 0; r < 4; ++r) {
            const int gr = m0 + wm + i * 16 + fr + r;
            const bool ok = gr < count;
            unsigned int pk[4];
            #pragma unroll
            for (int j = 0; j < 4; ++j) {
                float v = acc[i][j][r];
                v = v > 0.f ? v * v : 0.f;
                unsigned short b = bf16bits(v);
                int other = __shfl_xor((int)b, 1, 64);
                pk[j] = (unsigned)b | ((unsigned)other << 16);
            }
            if (ok && !(lane & 1)) {
                __hip_bfloat16* hrow = hidden + (size_t)(e * N_TOK + gr) * H_DIM + n0 + wn + fm;
                #pragma unroll
                for (int j = 0; j < 4; ++j)
                    *reinterpret_cast<unsigned int*>(hrow + j * 16) = pk[j];
            }
        }
    }
}

// -- grouped down-proj (full K=2048, BN=64): out += w * (hidden @ w_down^T) --
__global__ void __launch_bounds__(256) down_kernel(
    const __hip_bfloat16* __restrict__ hidden, const __hip_bfloat16* __restrict__ wdb,
    const int* __restrict__ tok_list, const float* __restrict__ wlist,
    const int* __restrict__ cnt, float* __restrict__ out)
{
    // bijective XCD swizzle: grid = 16 x 32 x 8 = 4096 blocks
    const int lid = (blockIdx.z * 32 + blockIdx.y) * 16 + blockIdx.x;
    const int s   = (lid & 7) * 512 + (lid >> 3);
    const int bx = s & 15, by = (s >> 4) & 31, bz = s >> 9;

    const int e = bz;
    const int count = cnt[e];
    const int m0 = by * BM;
    if (m0 >= count) return;
    const int n0 = bx * BND;

    __shared__ __hip_bfloat16 lA[2 * HALF_ELEMS];   // 2 halves x 128x32
    __shared__ __hip_bfloat16 lB[2 * HALF_B];       // 2 halves x  64x32

    const int tid  = threadIdx.x;
    const int lane = tid & 63;
    const int wv   = tid >> 6;
    const int wm = (wv >> 1) * 64;
    const int wn = (wv & 1) * 32;

    // A staging: seg = wv+4t covers rows seg*16..+15 (128 rows)
    const __hip_bfloat16* ga[2];
    __hip_bfloat16* la[2];
    #pragma unroll
    for (int t = 0; t < 2; ++t) {
        const int srow = (wv + 4 * t) * 16 + (lane >> 2);
        int r = m0 + srow;
        const int arow = e * N_TOK + (r < count ? r : count - 1);
        ga[t] = hidden + (size_t)arow * H_DIM + (lane & 3) * 8;
        la[t] = lA + (wv + 4 * t) * 512;
    }
    // B staging: seg = wv covers rows wv*16..+15 (64 rows)
    const int srowB = wv * 16 + (lane >> 2);
    const __hip_bfloat16* gb = wdb + (size_t)e * C_DIM * H_DIM
                             + (size_t)(n0 + srowB) * H_DIM + (lane & 3) * 8;
    __hip_bfloat16* lb = lB + wv * 512;

    f32x4 acc[4][2];
    #pragma unroll
    for (int i = 0; i < 4; ++i)
        #pragma unroll
        for (int j = 0; j < 2; ++j)
            acc[i][j] = (f32x4){0.f, 0.f, 0.f, 0.f};

    const int fm  = lane & 15;
    const int fkb = (lane >> 4) * 8;

    for (int k0 = 0; k0 < H_DIM; k0 += 2 * HKE) {
        __syncthreads();
        #pragma unroll
        for (int h = 0; h < 2; ++h) {
            #pragma unroll
            for (int t = 0; t < 2; ++t)
                gload16(ga[t] + h * HKE, la[t] + h * HALF_ELEMS);
            gload16(gb + h * HKE, lb + h * HALF_B);
        }
        #pragma unroll
        for (int t = 0; t < 2; ++t) ga[t] += 2 * HKE;
        gb += 2 * HKE;
        __syncthreads();
        #pragma unroll
        for (int h = 0; h < 2; ++h) {
            bf16x8 af[4], bfr[2];
            #pragma unroll
            for (int i = 0; i < 4; ++i)
                af[i]  = *reinterpret_cast<const bf16x8*>(lA + h * HALF_ELEMS + (wm + i * 16 + fm) * HKE + fkb);
            #pragma unroll
            for (int j = 0; j < 2; ++j)
                bfr[j] = *reinterpret_cast<const bf16x8*>(lB + h * HALF_B + (wn + j * 16 + fm) * HKE + fkb);
            #pragma unroll
            for (int i = 0; i < 4; ++i)
                #pragma unroll
                for (int j = 0; j < 2; ++j)
                    acc[i][j] = __builtin_amdgcn_mfma_f32_16x16x32_bf16(af[i], bfr[j], acc[i][j], 0, 0, 0);
        }
    }

    // epilogue: weighted atomic scatter straight into out (ve already there)
    const int fr = (lane >> 4) * 4;
    #pragma unroll
    for (int i = 0; i < 4; ++i) {
        #pragma unroll
        for (int r = 0; r < 4; ++r) {
            const int gr = m0 + wm + i * 16 + fr + r;
            if (gr < count) {
                const int   tok = tok_list[e * N_TOK + gr];
                const float w   = wlist[e * N_TOK + gr];
                float* orow = out + (size_t)tok * C_DIM + n0 + wn + fm;
                #pragma unroll
                for (int j = 0; j < 2; ++j)
                    __hip_atomic_fetch_add(orow + j * 16, w * acc[i][j][r],
                                           __ATOMIC_RELAXED, __HIP_MEMORY_SCOPE_AGENT);
            }
        }
    }
}

extern "C" void kernel_launch(void* const* d_in, const int* in_sizes, int n_in,
                              void* d_out, int out_size, void* d_ws, size_t ws_size,
                              hipStream_t stream)
{
    const float* x         = (const float*)d_in[0];
    const int*   token_ids = (const int*)  d_in[1];
    const float* w_up      = (const float*)d_in[2];
    const float* w_down    = (const float*)d_in[3];
    const float* router_w  = (const float*)d_in[4];
    const float* router_b  = (const float*)d_in[5];
    const float* ve_tables = (const float*)d_in[6];
    float* out = (float*)d_out;

    char* ws = (char*)d_ws;
    size_t off = 0;
    __hip_bfloat16* hidden  = (__hip_bfloat16*)(ws + off); off += (size_t)NE_MLP * N_TOK * H_DIM * 2;  // 134 MB
    __hip_bfloat16* xb      = (__hip_bfloat16*)(ws + off); off += (size_t)N_TOK * C_DIM * 2;
    __hip_bfloat16* wub     = (__hip_bfloat16*)(ws + off); off += (size_t)NE_MLP * H_DIM * C_DIM * 2;
    __hip_bfloat16* wdb     = (__hip_bfloat16*)(ws + off); off += (size_t)NE_MLP * C_DIM * H_DIM * 2;
    int*   tok_list = (int*)  (ws + off); off += (size_t)NE_MLP * N_TOK * 4;
    float* wlist    = (float*)(ws + off); off += (size_t)NE_MLP * N_TOK * 4;
    int*   cnt      = (int*)  (ws + off); off += 64;

    hipMemsetAsync(cnt, 0, NE_MLP * sizeof(int), stream);

    router_kernel<<<N_TOK / 4, 256, 0, stream>>>(x, router_w, router_b,
                                                 token_ids, ve_tables, xb,
                                                 tok_list, wlist, cnt, out);
    cvt_kernel<<<2 * CVT_W / 256, 256, 0, stream>>>(w_up, w_down, wub, wdb);
    up_kernel<<<dim3(H_DIM / BN, N_TOK / BM, NE_MLP), 256, 0, stream>>>(
        xb, wub, tok_list, cnt, hidden);
    down_kernel<<<dim3(C_DIM / BND, N_TOK / BM, NE_MLP), 256, 0, stream>>>(
        hidden, wdb, tok_list, wlist, cnt, out);
}